// Round 9
// baseline (133.455 us; speedup 1.0000x reference)
//
#include <hip/hip_runtime.h>
#include <math.h>

#define N 4096
#define D 256
#define NPOS 32768
#define TEMP 0.07f
#define INVT (1.0f / 0.07f)
#define BIGF 3.0e38f

#define RQ 5.5f                      // quantization range [-RQ, RQ]
#define QS (255.0f / (2.0f * RQ))    // f32 -> u8 scale
#define DEQ (2.0f * RQ / 255.0f)     // u8-units -> f32

#define NT 64          // 64-row stat-tiles per dim (partials layout)
#define NT2 32         // 128x128 block-tiles per dim
#define NTRI2 (NT2 * (NT2 + 1) / 2)  // 528 triangle blocks
#define KC 32          // k4 (u32) per D-chunk (=128 elements), 2 chunks
#define LP 132         // padded LDS row stride in u32 (16B-aligned, 2-way writes)

// workspace layout (floats):
// [0 .. N*64)         pmin[r][c]  (r = row, c = 64-col-tile)  row-major
// [N*64 .. 2*N*64)    psum[r][c]
// [2*N*64 .. +N)      t[r]
// [.. +1]             loss accumulator (float)
// [.. +1]             ticket counter (uint)
// [WS_XQ ..)          xq: N*(D/4) u32 of packed u8 quants
#define WS_PMIN 0
#define WS_PSUM (N * NT)
#define WS_T    (2 * N * NT)
#define WS_ACC  (2 * N * NT + N)
#define WS_CNT  (2 * N * NT + N + 1)
#define WS_XQ   (2 * N * NT + N + 4)   // 16B-aligned

__device__ __forceinline__ void sad_acc(unsigned a, unsigned b, unsigned& c) {
    // tied operand: in-place SAD, forces arch-VGPR allocation (no AGPR moves)
    asm("v_sad_u8 %0, %1, %2, %0" : "+v"(c) : "v"(a), "v"(b));
}

__device__ __forceinline__ unsigned quant1(float v) {
    const float f = fminf(fmaxf((v + RQ) * QS, 0.0f), 255.0f);
    return (unsigned)__float2uint_rn(f);
}

// quantize f32 -> packed u8 (4/u32), and zero acc/ticket
__global__ __launch_bounds__(256)
void cvt_init_k(const float* __restrict__ x, unsigned* __restrict__ xq,
                float* __restrict__ acc, unsigned* __restrict__ cnt) {
    const int i = blockIdx.x * 256 + threadIdx.x;  // over N*D/4
    const float4 v = ((const float4*)x)[i];
    const unsigned q = quant1(v.x) | (quant1(v.y) << 8) |
                       (quant1(v.z) << 16) | (quant1(v.w) << 24);
    xq[i] = q;
    if (i == 0) { *acc = 0.0f; *cnt = 0u; }
}

// 128x128 block-tile, 256 threads = 4 waves; wave (w0,w1) owns a 64x64
// quadrant, 8x8 micro-tile per lane. u8 SAD inner loop, hand-pipelined
// (next k4's frags loaded before this k4's SADs). LDS [k4][m] transposed
// with stride 132 u32: staging writes 2-way (free), frag b128 reads
// conflict-free. Staging global loads: 4 lanes/row -> 16 lines/instr.
__global__ __launch_bounds__(256, 2)
void dist_tile_k(const unsigned* __restrict__ xq,
                 float* __restrict__ pmin, float* __restrict__ psum) {
    // triangular decode: blockIdx.x -> (bm, bn), bm <= bn
    const int tt = blockIdx.x;
    const int u_ = (NTRI2 - 1) - tt;
    int r = (int)((sqrtf((float)(8 * u_ + 1)) - 1.0f) * 0.5f);
    while (r * (r + 1) / 2 > u_) --r;
    while ((r + 1) * (r + 2) / 2 <= u_) ++r;
    const int bm = (NT2 - 1) - r;
    const int bn = (NT2 - 1) - (u_ - r * (r + 1) / 2);

    const int tid = threadIdx.x;
    const int lane = tid & 63;
    const int w = tid >> 6;
    const int w0 = w >> 1;          // row quadrant
    const int w1 = w & 1;           // col quadrant
    const int tx = lane & 7;
    const int ty = lane >> 3;

    const int rt = 2 * bm + w0;     // 64-row-tile index
    const int ct = 2 * bn + w1;     // 64-col-tile index
    const bool diagq = (rt == ct);

    __shared__ unsigned As[KC][LP];  // 16.5 KB
    __shared__ unsigned Bs[KC][LP];  // 16.5 KB

    unsigned uacc[2][2][4][4];
#pragma unroll
    for (int rh = 0; rh < 2; ++rh)
#pragma unroll
        for (int ch = 0; ch < 2; ++ch)
#pragma unroll
            for (int i = 0; i < 4; ++i)
#pragma unroll
                for (int j = 0; j < 4; ++j) uacc[rh][ch][i][j] = 0u;

    const int rowA0 = bm * 128;
    const int rowB0 = bn * 128;

    // staging mapping: u = tid&3 (uint4 col), ra = tid>>2 (row 0..63)
    const int su = tid & 3;
    const int ra = tid >> 2;
    // row pointers in uint4 units (each row = 16 uint4)
    const uint4* gA0 = (const uint4*)xq + (size_t)(rowA0 + ra) * 16;
    const uint4* gA1 = (const uint4*)xq + (size_t)(rowA0 + ra + 64) * 16;
    const uint4* gB0 = (const uint4*)xq + (size_t)(rowB0 + ra) * 16;
    const uint4* gB1 = (const uint4*)xq + (size_t)(rowB0 + ra + 64) * 16;

    const int aoff = w0 * 64 + ty * 4;
    const int boff = w1 * 64 + tx * 4;

    for (int chk = 0; chk < 2; ++chk) {
        const int cb = chk * 8;
        const uint4 a00 = gA0[cb + su];     // k4' = su*4..+3, row ra
        const uint4 a01 = gA0[cb + su + 4]; // k4' = (su+4)*4..+3
        const uint4 a10 = gA1[cb + su];
        const uint4 a11 = gA1[cb + su + 4];
        const uint4 b00 = gB0[cb + su];
        const uint4 b01 = gB0[cb + su + 4];
        const uint4 b10 = gB1[cb + su];
        const uint4 b11 = gB1[cb + su + 4];
        __syncthreads();  // previous chunk's reads done before overwrite
        {
            const int k0 = su * 4, k1 = (su + 4) * 4;
            As[k0 + 0][ra] = a00.x; As[k0 + 1][ra] = a00.y;
            As[k0 + 2][ra] = a00.z; As[k0 + 3][ra] = a00.w;
            As[k1 + 0][ra] = a01.x; As[k1 + 1][ra] = a01.y;
            As[k1 + 2][ra] = a01.z; As[k1 + 3][ra] = a01.w;
            As[k0 + 0][ra + 64] = a10.x; As[k0 + 1][ra + 64] = a10.y;
            As[k0 + 2][ra + 64] = a10.z; As[k0 + 3][ra + 64] = a10.w;
            As[k1 + 0][ra + 64] = a11.x; As[k1 + 1][ra + 64] = a11.y;
            As[k1 + 2][ra + 64] = a11.z; As[k1 + 3][ra + 64] = a11.w;
            Bs[k0 + 0][ra] = b00.x; Bs[k0 + 1][ra] = b00.y;
            Bs[k0 + 2][ra] = b00.z; Bs[k0 + 3][ra] = b00.w;
            Bs[k1 + 0][ra] = b01.x; Bs[k1 + 1][ra] = b01.y;
            Bs[k1 + 2][ra] = b01.z; Bs[k1 + 3][ra] = b01.w;
            Bs[k0 + 0][ra + 64] = b10.x; Bs[k0 + 1][ra + 64] = b10.y;
            Bs[k0 + 2][ra + 64] = b10.z; Bs[k0 + 3][ra + 64] = b10.w;
            Bs[k1 + 0][ra + 64] = b11.x; Bs[k1 + 1][ra + 64] = b11.y;
            Bs[k1 + 2][ra + 64] = b11.z; Bs[k1 + 3][ra + 64] = b11.w;
        }
        __syncthreads();

        // hand-pipelined: load k4+1 frags before k4's SADs
        uint4 alo = *(const uint4*)&As[0][aoff];
        uint4 ahi = *(const uint4*)&As[0][aoff + 32];
        uint4 blo = *(const uint4*)&Bs[0][boff];
        uint4 bhi = *(const uint4*)&Bs[0][boff + 32];
#pragma unroll 4
        for (int k4 = 0; k4 < KC; ++k4) {
            const int kn = (k4 + 1) & (KC - 1);
            const uint4 nal = *(const uint4*)&As[kn][aoff];
            const uint4 nah = *(const uint4*)&As[kn][aoff + 32];
            const uint4 nbl = *(const uint4*)&Bs[kn][boff];
            const uint4 nbh = *(const uint4*)&Bs[kn][boff + 32];
            const unsigned av[2][4] = {{alo.x, alo.y, alo.z, alo.w},
                                       {ahi.x, ahi.y, ahi.z, ahi.w}};
            const unsigned bv[2][4] = {{blo.x, blo.y, blo.z, blo.w},
                                       {bhi.x, bhi.y, bhi.z, bhi.w}};
#pragma unroll
            for (int rh = 0; rh < 2; ++rh)
#pragma unroll
                for (int chq = 0; chq < 2; ++chq)
#pragma unroll
                    for (int i = 0; i < 4; ++i)
#pragma unroll
                        for (int j = 0; j < 4; ++j)
                            sad_acc(av[rh][i], bv[chq][j], uacc[rh][chq][i][j]);
            alo = nal; ahi = nah; blo = nbl; bhi = nbh;
        }
    }

    // dequantize to float
    float acc[2][2][4][4];
#pragma unroll
    for (int rh = 0; rh < 2; ++rh)
#pragma unroll
        for (int chq = 0; chq < 2; ++chq)
#pragma unroll
            for (int i = 0; i < 4; ++i)
#pragma unroll
                for (int j = 0; j < 4; ++j)
                    acc[rh][chq][i][j] = (float)uacc[rh][chq][i][j] * DEQ;

    // diagonal exclusion: poison self-distance (min skips it, exp -> 0)
    if (diagq) {
#pragma unroll
        for (int rh = 0; rh < 2; ++rh)
#pragma unroll
            for (int chq = 0; chq < 2; ++chq)
#pragma unroll
                for (int i = 0; i < 4; ++i)
#pragma unroll
                    for (int j = 0; j < 4; ++j)
                        if (rh * 32 + ty * 4 + i == chq * 32 + tx * 4 + j)
                            acc[rh][chq][i][j] = BIGF;
    }

    // ---- row stats (iff rt <= ct): my 8 cols + shfl across tx lanes ----
    if (rt <= ct) {
#pragma unroll
        for (int rh = 0; rh < 2; ++rh) {
#pragma unroll
            for (int i = 0; i < 4; ++i) {
                float mn = BIGF;
#pragma unroll
                for (int chq = 0; chq < 2; ++chq)
#pragma unroll
                    for (int j = 0; j < 4; ++j) mn = fminf(mn, acc[rh][chq][i][j]);
                mn = fminf(mn, __shfl_xor(mn, 1, 64));
                mn = fminf(mn, __shfl_xor(mn, 2, 64));
                mn = fminf(mn, __shfl_xor(mn, 4, 64));
                float s = 0.0f;
#pragma unroll
                for (int chq = 0; chq < 2; ++chq)
#pragma unroll
                    for (int j = 0; j < 4; ++j)
                        s += __expf((mn - acc[rh][chq][i][j]) * INVT);
                s += __shfl_xor(s, 1, 64);
                s += __shfl_xor(s, 2, 64);
                s += __shfl_xor(s, 4, 64);
                if (tx == 0) {
                    const size_t idx =
                        (size_t)(rt * 64 + rh * 32 + ty * 4 + i) * NT + ct;
                    pmin[idx] = mn;
                    psum[idx] = s;
                }
            }
        }
    }

    // ---- col stats (iff rt < ct): my 8 rows + shfl across ty lanes ----
    if (rt < ct) {
#pragma unroll
        for (int chq = 0; chq < 2; ++chq) {
#pragma unroll
            for (int j = 0; j < 4; ++j) {
                float mn = BIGF;
#pragma unroll
                for (int rh = 0; rh < 2; ++rh)
#pragma unroll
                    for (int i = 0; i < 4; ++i) mn = fminf(mn, acc[rh][chq][i][j]);
                mn = fminf(mn, __shfl_xor(mn, 8, 64));
                mn = fminf(mn, __shfl_xor(mn, 16, 64));
                mn = fminf(mn, __shfl_xor(mn, 32, 64));
                float s = 0.0f;
#pragma unroll
                for (int rh = 0; rh < 2; ++rh)
#pragma unroll
                    for (int i = 0; i < 4; ++i)
                        s += __expf((mn - acc[rh][chq][i][j]) * INVT);
                s += __shfl_xor(s, 8, 64);
                s += __shfl_xor(s, 16, 64);
                s += __shfl_xor(s, 32, 64);
                if (ty == 0) {
                    const size_t idx =
                        (size_t)(ct * 64 + chq * 32 + tx * 4 + j) * NT + rt;
                    pmin[idx] = mn;
                    psum[idx] = s;
                }
            }
        }
    }
}

// One wave per row: coalesced read of the 64 partials, shuffle reduce.
__global__ __launch_bounds__(256)
void row_stats_k(const float* __restrict__ pmin, const float* __restrict__ psum,
                 float* __restrict__ t) {
    const int r = blockIdx.x * 4 + (threadIdx.x >> 6);
    const int c = threadIdx.x & 63;
    const float pm = pmin[(size_t)r * NT + c];
    const float ps = psum[(size_t)r * NT + c];
    float mn = pm;
#pragma unroll
    for (int off = 32; off > 0; off >>= 1) mn = fminf(mn, __shfl_xor(mn, off, 64));
    float s = ps * __expf((mn - pm) * INVT);
#pragma unroll
    for (int off = 32; off > 0; off >>= 1) s += __shfl_xor(s, off, 64);
    if (c == 0) t[r] = TEMP * __logf(s) - mn;
}

// 1024 blocks x 4 waves x 8 pairs; batched index+data loads; block-level
// atomic + ticket: last block finalizes the loss.
__global__ __launch_bounds__(256)
void pair_fin_k(const float* __restrict__ x, const int* __restrict__ row,
                const int* __restrict__ col, const float* __restrict__ t,
                float* __restrict__ acc, unsigned* __restrict__ cnt,
                float* __restrict__ out) {
    const int lane = threadIdx.x & 63;
    const int wave = threadIdx.x >> 6;
    const int p0 = (blockIdx.x * 4 + wave) * 8;

    int rp[8], cp[8];
#pragma unroll
    for (int i = 0; i < 8; ++i) { rp[i] = row[p0 + i]; cp[i] = col[p0 + i]; }
    float4 a[8], b[8];
#pragma unroll
    for (int i = 0; i < 8; ++i) {
        a[i] = *(const float4*)&x[(size_t)rp[i] * D + lane * 4];
        b[i] = *(const float4*)&x[(size_t)cp[i] * D + lane * 4];
    }
    float wsum = 0.0f;
#pragma unroll
    for (int i = 0; i < 8; ++i) {
        float d = fabsf(a[i].x - b[i].x) + fabsf(a[i].y - b[i].y) +
                  fabsf(a[i].z - b[i].z) + fabsf(a[i].w - b[i].w);
#pragma unroll
        for (int off = 32; off > 0; off >>= 1) d += __shfl_xor(d, off, 64);
        if (lane == 0) wsum += d + t[rp[i]];
    }

    __shared__ float bs[4];
    if (lane == 0) bs[wave] = wsum;
    __syncthreads();
    if (threadIdx.x == 0) {
        const float tot = bs[0] + bs[1] + bs[2] + bs[3];
        atomicAdd(acc, tot);
        __threadfence();
        const unsigned tk = atomicAdd(cnt, 1u);
        if (tk == (unsigned)(gridDim.x - 1)) {
            const float v = atomicAdd(acc, 0.0f);  // coherent read
            out[0] = v * (1.0f / (float)NPOS);
        }
    }
}

extern "C" void kernel_launch(void* const* d_in, const int* in_sizes, int n_in,
                              void* d_out, int out_size, void* d_ws, size_t ws_size,
                              hipStream_t stream) {
    const float* x = (const float*)d_in[0];
    const int* row = (const int*)d_in[1];
    const int* col = (const int*)d_in[2];
    float* ws = (float*)d_ws;
    float* out = (float*)d_out;
    unsigned* xq = (unsigned*)(ws + WS_XQ);
    float* acc = ws + WS_ACC;
    unsigned* cnt = (unsigned*)(ws + WS_CNT);

    cvt_init_k<<<(N * D / 4) / 256, 256, 0, stream>>>(x, xq, acc, cnt);

    dist_tile_k<<<NTRI2, 256, 0, stream>>>(xq, ws + WS_PMIN, ws + WS_PSUM);

    row_stats_k<<<N / 4, 256, 0, stream>>>(ws + WS_PMIN, ws + WS_PSUM, ws + WS_T);

    pair_fin_k<<<NPOS / 32, 256, 0, stream>>>(x, row, col, ws + WS_T, acc, cnt, out);
}